// Round 1
// baseline (1505.428 us; speedup 1.0000x reference)
//
#include <hip/hip_runtime.h>
#include <hip/hip_bf16.h>

// Problem constants
#define Bb 4
#define Ls 1024
#define Dd 1024
#define Nn 16
#define Hh 64
#define Rr 2048

// ---------------------------------------------------------------------------
// Generic f32 tiled GEMM: C[M x N'] = A[M x K] * B[K x N'] (+bias) (+residual)
// 64x64 tile, BK=16, 256 threads, 4x4 microtile.
// ---------------------------------------------------------------------------
#define TS 64
#define BK 16

__global__ __launch_bounds__(256) void gemm64(
    const float* __restrict__ A, int lda, long aStride,
    const float* __restrict__ B, int ldb, long bStride,
    float* __restrict__ C, int ldc, long cStride,
    const float* __restrict__ bias,       // len N' or null
    const float* __restrict__ residual,   // M x N' or null
    int ldr, int K)
{
    const int batch = blockIdx.z;
    A += (long)batch * aStride;
    B += (long)batch * bStride;
    C += (long)batch * cStride;

    const int row0 = blockIdx.y * TS;
    const int col0 = blockIdx.x * TS;

    __shared__ float As[BK][TS + 4];  // As[k][i]
    __shared__ float Bs[BK][TS + 4];  // Bs[k][j]

    const int tid = threadIdx.x;
    const int tr = tid >> 4;    // 0..15
    const int tc = tid & 15;    // 0..15

    float acc[4][4];
#pragma unroll
    for (int a = 0; a < 4; ++a)
#pragma unroll
        for (int b2 = 0; b2 < 4; ++b2) acc[a][b2] = 0.f;

    for (int k0 = 0; k0 < K; k0 += BK) {
        // Load A tile (64 rows x 16 k) transposed into As[k][i]
        {
            const int i = tid >> 2;            // 0..63
            const int kq = (tid & 3) * 4;      // 0,4,8,12
            const float4 v = *(const float4*)(A + (long)(row0 + i) * lda + k0 + kq);
            As[kq + 0][i] = v.x;
            As[kq + 1][i] = v.y;
            As[kq + 2][i] = v.z;
            As[kq + 3][i] = v.w;
        }
        // Load B tile (16 k x 64 cols)
        {
            const int kk = tid >> 4;           // 0..15
            const int jq = (tid & 15) * 4;     // 0..60
            const float4 v = *(const float4*)(B + (long)(k0 + kk) * ldb + col0 + jq);
            *(float4*)&Bs[kk][jq] = v;
        }
        __syncthreads();

#pragma unroll
        for (int kk = 0; kk < BK; ++kk) {
            const float4 av = *(const float4*)&As[kk][tr * 4];
            const float4 bv = *(const float4*)&Bs[kk][tc * 4];
            float a[4] = {av.x, av.y, av.z, av.w};
            float b[4] = {bv.x, bv.y, bv.z, bv.w};
#pragma unroll
            for (int ii = 0; ii < 4; ++ii)
#pragma unroll
                for (int jj = 0; jj < 4; ++jj) acc[ii][jj] += a[ii] * b[jj];
        }
        __syncthreads();
    }

    // Epilogue
    const int c0 = col0 + tc * 4;
    float4 bval = make_float4(0.f, 0.f, 0.f, 0.f);
    if (bias) bval = *(const float4*)(bias + c0);
#pragma unroll
    for (int ii = 0; ii < 4; ++ii) {
        const int r = row0 + tr * 4 + ii;
        float4 v = make_float4(acc[ii][0] + bval.x, acc[ii][1] + bval.y,
                               acc[ii][2] + bval.z, acc[ii][3] + bval.w);
        if (residual) {
            const float4 rr = *(const float4*)(residual + (long)r * ldr + c0);
            v.x += rr.x; v.y += rr.y; v.z += rr.z; v.w += rr.w;
        }
        *(float4*)&C[(long)r * ldc + c0] = v;
    }
}

// ---------------------------------------------------------------------------
// Attention: per (b, n, 32-query tile) flash-style with relative-pos band.
// pos[l,m] = dot(qh[l]+r_r_bias, r[1024+m-l]); band row local idx = 31+j-i.
// Writes output IN-PLACE over qh rows (this block is the unique reader).
// ---------------------------------------------------------------------------
#define BLq 32
#define BMk 32

__global__ __launch_bounds__(256) void attn_kernel(
    float* qh,                           // (B*L, N*H) row-major; also output!
    const float* __restrict__ kh,
    const float* __restrict__ vh,
    const float* __restrict__ rS,        // (N, R, H)
    const int* __restrict__ padding,     // (B, L) int32 0/1
    const float* __restrict__ rwb,       // (N, H)
    const float* __restrict__ rrb)       // (N, H)
{
    const int lt = blockIdx.x;
    const int n  = blockIdx.y;
    const int b  = blockIdx.z;
    const int l0 = lt * BLq;

    __shared__ float qw[BLq][Hh + 4];
    __shared__ float qr[BLq][Hh + 4];
    __shared__ float ks[BMk][Hh + 4];
    __shared__ float vs[BMk][Hh + 4];
    __shared__ float rs[63][Hh + 4];
    __shared__ float ps[BLq][BMk + 4];
    __shared__ int   pad_s[BMk];

    const int tid = threadIdx.x;
    const int i   = tid >> 3;       // row 0..31
    const int sub = tid & 7;        // 0..7

    // Load q tile, make both biased copies
    {
        const int f = sub * 8;
        const float* src = qh + ((long)(b * Ls + l0 + i) * Nn + n) * Hh + f;
        const float* wb = rwb + n * Hh + f;
        const float* rb = rrb + n * Hh + f;
#pragma unroll
        for (int u = 0; u < 8; ++u) {
            const float v = src[u];
            qw[i][f + u] = v + wb[u];
            qr[i][f + u] = v + rb[u];
        }
    }

    float rmax = -INFINITY, rsum = 0.f;
    float acc[8];
#pragma unroll
    for (int u = 0; u < 8; ++u) acc[u] = 0.f;

    for (int mt = 0; mt < Ls / BMk; ++mt) {
        const int m0 = mt * BMk;
        __syncthreads();   // protect LDS from previous iteration readers

        // Load K and V tiles
        {
            const int f = sub * 8;
            const float* ksrc = kh + ((long)(b * Ls + m0 + i) * Nn + n) * Hh + f;
            const float* vsrc = vh + ((long)(b * Ls + m0 + i) * Nn + n) * Hh + f;
#pragma unroll
            for (int u = 0; u < 8; ++u) {
                ks[i][f + u] = ksrc[u];
                vs[i][f + u] = vsrc[u];
            }
        }
        // Load r band: c = c0 + rr_i, rr_i in [0,63)
        {
            const int c0 = 1024 + m0 - (l0 + BLq - 1);
            for (int idx = tid; idx < 63 * 16; idx += 256) {
                const int rrow = idx >> 4;
                const int q4 = (idx & 15) * 4;
                *(float4*)&rs[rrow][q4] =
                    *(const float4*)(rS + ((long)n * Rr + (c0 + rrow)) * Hh + q4);
            }
            if (tid < BMk) pad_s[tid] = padding[b * Ls + m0 + tid];
        }
        __syncthreads();

        // Scores: thread (i, sub) computes j = sub*4 .. sub*4+3
        const int jbase = sub * 4;
        float sc[4] = {0.f, 0.f, 0.f, 0.f};
        float sr[4] = {0.f, 0.f, 0.f, 0.f};
#pragma unroll
        for (int h4 = 0; h4 < 16; ++h4) {
            const float4 a  = *(const float4*)&qw[i][h4 * 4];
            const float4 aq = *(const float4*)&qr[i][h4 * 4];
#pragma unroll
            for (int jj = 0; jj < 4; ++jj) {
                const int j = jbase + jj;
                const float4 kv = *(const float4*)&ks[j][h4 * 4];
                const float4 rv = *(const float4*)&rs[31 + j - i][h4 * 4];
                sc[jj] += a.x * kv.x + a.y * kv.y + a.z * kv.z + a.w * kv.w;
                sr[jj] += aq.x * rv.x + aq.y * rv.y + aq.z * rv.z + aq.w * rv.w;
            }
        }
        float s[4];
        float tmax = -INFINITY;
#pragma unroll
        for (int jj = 0; jj < 4; ++jj) {
            const int j = jbase + jj;
            s[jj] = 0.125f * (sc[jj] + sr[jj]) - 1.0e6f * (float)pad_s[j];
            tmax = fmaxf(tmax, s[jj]);
        }
        // max over the 8 lanes of this row (consecutive lanes, same wave)
#pragma unroll
        for (int off = 1; off < 8; off <<= 1)
            tmax = fmaxf(tmax, __shfl_xor(tmax, off, 64));

        const float mnew = fmaxf(rmax, tmax);
        const float alpha = __expf(rmax - mnew);
        float psum = 0.f;
#pragma unroll
        for (int jj = 0; jj < 4; ++jj) {
            const float p = __expf(s[jj] - mnew);
            ps[i][jbase + jj] = p;
            psum += p;
        }
#pragma unroll
        for (int off = 1; off < 8; off <<= 1) psum += __shfl_xor(psum, off, 64);

        rsum = rsum * alpha + psum;
        rmax = mnew;
#pragma unroll
        for (int u = 0; u < 8; ++u) acc[u] *= alpha;

        __syncthreads();   // ps visible to all (and safe ordering)

        // PV: acc[h] += sum_j p[i][j] * vs[j][h],  h = sub*8 .. +7
#pragma unroll
        for (int j4 = 0; j4 < 8; ++j4) {
            const float4 pv = *(const float4*)&ps[i][j4 * 4];
            const float pj[4] = {pv.x, pv.y, pv.z, pv.w};
#pragma unroll
            for (int jj = 0; jj < 4; ++jj) {
                const int j = j4 * 4 + jj;
                const float4 v0 = *(const float4*)&vs[j][sub * 8];
                const float4 v1 = *(const float4*)&vs[j][sub * 8 + 4];
                acc[0] += pj[jj] * v0.x; acc[1] += pj[jj] * v0.y;
                acc[2] += pj[jj] * v0.z; acc[3] += pj[jj] * v0.w;
                acc[4] += pj[jj] * v1.x; acc[5] += pj[jj] * v1.y;
                acc[6] += pj[jj] * v1.z; acc[7] += pj[jj] * v1.w;
            }
        }
    }

    const float inv = 1.f / rsum;
    float* dst = qh + ((long)(b * Ls + l0 + i) * Nn + n) * Hh + sub * 8;
#pragma unroll
    for (int u = 0; u < 8; ++u) dst[u] = acc[u] * inv;
}

// ---------------------------------------------------------------------------
// LayerNorm in-place over rows of x (4096 x 1024)
// ---------------------------------------------------------------------------
__global__ __launch_bounds__(256) void ln_kernel(
    float* x, const float* __restrict__ g, const float* __restrict__ bb)
{
    const int row = blockIdx.x;
    const int tid = threadIdx.x;
    float4 v = ((const float4*)(x + (long)row * Dd))[tid];
    float s  = v.x + v.y + v.z + v.w;
    float sq = v.x * v.x + v.y * v.y + v.z * v.z + v.w * v.w;
#pragma unroll
    for (int off = 32; off; off >>= 1) {
        s  += __shfl_down(s, off, 64);
        sq += __shfl_down(sq, off, 64);
    }
    __shared__ float ws_s[4], ws_q[4];
    __shared__ float s_mu, s_rstd;
    const int wave = tid >> 6, lane = tid & 63;
    if (lane == 0) { ws_s[wave] = s; ws_q[wave] = sq; }
    __syncthreads();
    if (tid == 0) {
        const float ts = ws_s[0] + ws_s[1] + ws_s[2] + ws_s[3];
        const float tq = ws_q[0] + ws_q[1] + ws_q[2] + ws_q[3];
        const float mu = ts / (float)Dd;
        const float var = tq / (float)Dd - mu * mu;
        s_mu = mu;
        s_rstd = rsqrtf(var + 1e-5f);
    }
    __syncthreads();
    const float mu = s_mu, rstd = s_rstd;
    const float4 gv = ((const float4*)g)[tid];
    const float4 bv = ((const float4*)bb)[tid];
    float4 o;
    o.x = (v.x - mu) * rstd * gv.x + bv.x;
    o.y = (v.y - mu) * rstd * gv.y + bv.y;
    o.z = (v.z - mu) * rstd * gv.z + bv.z;
    o.w = (v.w - mu) * rstd * gv.w + bv.w;
    ((float4*)(x + (long)row * Dd))[tid] = o;
}

// ---------------------------------------------------------------------------
extern "C" void kernel_launch(void* const* d_in, const int* in_sizes, int n_in,
                              void* d_out, int out_size, void* d_ws, size_t ws_size,
                              hipStream_t stream) {
    const float* q      = (const float*)d_in[0];
    const float* k      = (const float*)d_in[1];
    const float* v      = (const float*)d_in[2];
    const float* posenc = (const float*)d_in[3];
    const int*   pad    = (const int*)  d_in[4];
    const float* q_w    = (const float*)d_in[5];
    const float* k_w    = (const float*)d_in[6];
    const float* k_b    = (const float*)d_in[7];
    const float* v_w    = (const float*)d_in[8];
    const float* v_b    = (const float*)d_in[9];
    const float* rwb    = (const float*)d_in[10];
    const float* rrb    = (const float*)d_in[11];
    const float* r_ker  = (const float*)d_in[12];
    const float* post_w = (const float*)d_in[13];
    const float* post_b = (const float*)d_in[14];
    const float* ln_g   = (const float*)d_in[15];
    const float* ln_b   = (const float*)d_in[16];
    float* out = (float*)d_out;

    float* ws = (float*)d_ws;
    const long M4 = (long)Bb * Ls * Nn * Hh;   // 4096*1024
    float* qh = ws;
    float* kh = ws + M4;
    float* vh = ws + 2 * M4;
    float* rS = ws + 3 * M4;                   // N*R*H = 2M floats

    const dim3 blk(256);
    const int M = Bb * Ls;        // 4096
    const int NH = Nn * Hh;       // 1024

    // QKV projections: (4096 x 1024) * (1024 x 1024)
    gemm64<<<dim3(NH / TS, M / TS, 1), blk, 0, stream>>>(
        q, Dd, 0, q_w, NH, 0, qh, NH, 0, nullptr, nullptr, 0, Dd);
    gemm64<<<dim3(NH / TS, M / TS, 1), blk, 0, stream>>>(
        k, Dd, 0, k_w, NH, 0, kh, NH, 0, k_b, nullptr, 0, Dd);
    gemm64<<<dim3(NH / TS, M / TS, 1), blk, 0, stream>>>(
        v, Dd, 0, v_w, NH, 0, vh, NH, 0, v_b, nullptr, 0, Dd);

    // r projection: per n, (2048 x 1024) * (1024 x 64)
    gemm64<<<dim3(1, Rr / TS, Nn), blk, 0, stream>>>(
        posenc, Dd, 0, r_ker, Hh, (long)Dd * Hh, rS, Hh, (long)Rr * Hh,
        nullptr, nullptr, 0, Dd);

    // Attention (writes in-place over qh)
    attn_kernel<<<dim3(Ls / BLq, Nn, Bb), blk, 0, stream>>>(
        qh, kh, vh, rS, pad, rwb, rrb);

    // Post projection + bias + residual: (4096 x 1024) * (1024 x 1024)
    gemm64<<<dim3(Dd / TS, M / TS, 1), blk, 0, stream>>>(
        qh, NH, 0, post_w, Dd, 0, out, Dd, 0, post_b, q, Dd, Dd);

    // LayerNorm in-place on out
    ln_kernel<<<dim3(M), blk, 0, stream>>>(out, ln_g, ln_b);
}

// Round 2
// 789.133 us; speedup vs baseline: 1.9077x; 1.9077x over previous
//
#include <hip/hip_runtime.h>
#include <hip/hip_bf16.h>

// Problem constants
#define Bb 4
#define Ls 1024
#define Dd 1024
#define Nn 16
#define Hh 64
#define Rr 2048

typedef __attribute__((ext_vector_type(8))) short short8;
typedef __attribute__((ext_vector_type(4))) float f32x4;

__device__ __forceinline__ float bf2f(short s) {
    union { unsigned u; float f; } c;
    c.u = ((unsigned)(unsigned short)s) << 16;
    return c.f;
}
__device__ __forceinline__ short f2bf(float f) {
    __hip_bfloat16 h = __float2bfloat16(f);
    return *reinterpret_cast<short*>(&h);
}

// ---------------------------------------------------------------------------
// Generic f32 tiled GEMM: C[M x N'] = A[M x K] * B[K x N'] (+bias) (+residual)
// 64x64 tile, BK=16, 256 threads, 4x4 microtile. Optional bf16 output.
// ---------------------------------------------------------------------------
#define TS 64
#define BK 16

__global__ __launch_bounds__(256) void gemm64(
    const float* __restrict__ A, int lda, long aStride,
    const float* __restrict__ B, int ldb, long bStride,
    void* __restrict__ Cv, int ldc, long cStride, int out_bf16,
    const float* __restrict__ bias,       // len N' or null
    const float* __restrict__ residual,   // M x N' or null
    int ldr, int K)
{
    const int batch = blockIdx.z;
    A += (long)batch * aStride;
    B += (long)batch * bStride;

    const int row0 = blockIdx.y * TS;
    const int col0 = blockIdx.x * TS;

    __shared__ float As[BK][TS + 4];  // As[k][i]
    __shared__ float Bs[BK][TS + 4];  // Bs[k][j]

    const int tid = threadIdx.x;
    const int tr = tid >> 4;    // 0..15
    const int tc = tid & 15;    // 0..15

    float acc[4][4];
#pragma unroll
    for (int a = 0; a < 4; ++a)
#pragma unroll
        for (int b2 = 0; b2 < 4; ++b2) acc[a][b2] = 0.f;

    for (int k0 = 0; k0 < K; k0 += BK) {
        {
            const int i = tid >> 2;
            const int kq = (tid & 3) * 4;
            const float4 v = *(const float4*)(A + (long)(row0 + i) * lda + k0 + kq);
            As[kq + 0][i] = v.x;
            As[kq + 1][i] = v.y;
            As[kq + 2][i] = v.z;
            As[kq + 3][i] = v.w;
        }
        {
            const int kk = tid >> 4;
            const int jq = (tid & 15) * 4;
            const float4 v = *(const float4*)(B + (long)(k0 + kk) * ldb + col0 + jq);
            *(float4*)&Bs[kk][jq] = v;
        }
        __syncthreads();

#pragma unroll
        for (int kk = 0; kk < BK; ++kk) {
            const float4 av = *(const float4*)&As[kk][tr * 4];
            const float4 bv = *(const float4*)&Bs[kk][tc * 4];
            float a[4] = {av.x, av.y, av.z, av.w};
            float b[4] = {bv.x, bv.y, bv.z, bv.w};
#pragma unroll
            for (int ii = 0; ii < 4; ++ii)
#pragma unroll
                for (int jj = 0; jj < 4; ++jj) acc[ii][jj] += a[ii] * b[jj];
        }
        __syncthreads();
    }

    const int c0 = col0 + tc * 4;
    float4 bval = make_float4(0.f, 0.f, 0.f, 0.f);
    if (bias) bval = *(const float4*)(bias + c0);
#pragma unroll
    for (int ii = 0; ii < 4; ++ii) {
        const int r = row0 + tr * 4 + ii;
        float vals[4] = {acc[ii][0] + bval.x, acc[ii][1] + bval.y,
                         acc[ii][2] + bval.z, acc[ii][3] + bval.w};
        if (residual) {
            const float4 rr = *(const float4*)(residual + (long)r * ldr + c0);
            vals[0] += rr.x; vals[1] += rr.y; vals[2] += rr.z; vals[3] += rr.w;
        }
        if (out_bf16) {
            short* Cb = (short*)Cv + (long)batch * cStride;
#pragma unroll
            for (int jj = 0; jj < 4; ++jj)
                Cb[(long)r * ldc + c0 + jj] = f2bf(vals[jj]);
        } else {
            float* Cf = (float*)Cv + (long)batch * cStride;
            *(float4*)&Cf[(long)r * ldc + c0] =
                make_float4(vals[0], vals[1], vals[2], vals[3]);
        }
    }
}

// ---------------------------------------------------------------------------
// MFMA attention. Block = 256 threads = 4 waves; 64 queries/block (16/wave),
// 64-key tiles. bf16 inputs, f32 output.
// pos[l,m] = (q+rrb)·r[1024+m-l]; per wave band GEMM Pr (16x80), skew-gather
// with p = 16t + j - i + 15.  MFMA 16x16x32 layouts:
//   A[m=lane&15][k=quad*8+j], B[k=quad*8+j][n=lane&15],
//   C/D: col=lane&15, row=quad*4+reg.
// ---------------------------------------------------------------------------
__global__ __launch_bounds__(256) void attn_mfma(
    const short* __restrict__ qh, const short* __restrict__ kh,
    const short* __restrict__ vh, const short* __restrict__ rS,
    const int* __restrict__ padding, const float* __restrict__ rwb,
    const float* __restrict__ rrb, float* __restrict__ ao)
{
    const int lt = blockIdx.x, n = blockIdx.y, b = blockIdx.z;
    const int l0 = lt * 64;
    const int tid  = threadIdx.x;
    const int w    = tid >> 6;
    const int lane = tid & 63;
    const int quad = lane >> 4;
    const int ln16 = lane & 15;

    // strides padded to 72 shorts (144B) -> bank-spread ds_read_b128
    __shared__ short ks[64][72];        // K tile [key][h]
    __shared__ short vsT[64][72];       // V^T tile [h][key]
    __shared__ short rband[128][72];    // r band rows
    __shared__ float prl[4][16][83];    // per-wave Pr spill
    __shared__ short psm[4][16][72];    // per-wave P (bf16, A-layout source)
    __shared__ float pads[64];

    // Q fragments (A-layout), biased two ways, loaded once
    short8 qwf[2], qrf[2];
    {
        const long rowoff = ((long)(b * Ls + l0 + w * 16 + ln16)) * (Nn * Hh) + n * Hh;
#pragma unroll
        for (int c = 0; c < 2; ++c) {
            const int kb = c * 32 + quad * 8;
            short8 qv = *(const short8*)(qh + rowoff + kb);
#pragma unroll
            for (int j = 0; j < 8; ++j) {
                float qf = bf2f(qv[j]);
                qwf[c][j] = f2bf(qf + rwb[n * Hh + kb + j]);
                qrf[c][j] = f2bf(qf + rrb[n * Hh + kb + j]);
            }
        }
    }

    float m_r[4], l_r[4];
    f32x4 accO[4];
#pragma unroll
    for (int r = 0; r < 4; ++r) { m_r[r] = -INFINITY; l_r[r] = 0.f; }
#pragma unroll
    for (int t = 0; t < 4; ++t) accO[t] = (f32x4){0.f, 0.f, 0.f, 0.f};

    const int bw = 48 - 16 * w;   // wave's band base row

    for (int mt = 0; mt < Ls / 64; ++mt) {
        const int m0 = mt * 64;
        __syncthreads();

        // ---- stage K tile ----
#pragma unroll
        for (int p = 0; p < 2; ++p) {
            int idx = tid + p * 256;
            int r_ = idx >> 3, cq = (idx & 7) * 8;
            *(short8*)&ks[r_][cq] =
                *(const short8*)(kh + ((long)(b * Ls + m0 + r_)) * 1024 + n * 64 + cq);
        }
        // ---- stage V transposed (paired keys -> dword stores) ----
        {
            int kp = tid & 31, cq = (tid >> 5) * 8;
            const short* vp = vh + ((long)(b * Ls + m0 + 2 * kp)) * 1024 + n * 64 + cq;
            short8 va = *(const short8*)vp;
            short8 vb2 = *(const short8*)(vp + 1024);
#pragma unroll
            for (int u = 0; u < 8; ++u) {
                unsigned pk = ((unsigned)(unsigned short)va[u]) |
                              (((unsigned)(unsigned short)vb2[u]) << 16);
                *(unsigned*)&vsT[cq + u][2 * kp] = pk;
            }
        }
        // ---- stage r band: global row = cb + r_, 127 valid rows ----
        {
            const int cb = 961 - l0 + m0;   // in [1,1921]; cb+126 <= 2047
#pragma unroll
            for (int p = 0; p < 4; ++p) {
                int idx = tid + p * 256;
                int r_ = idx >> 3, cq = (idx & 7) * 8;
                if (r_ < 127) {
                    *(short8*)&rband[r_][cq] =
                        *(const short8*)(rS + ((long)n * Rr + cb + r_) * 64 + cq);
                } else {
                    *(short8*)&rband[r_][cq] = (short8)0;
                }
            }
        }
        if (tid < 64) pads[tid] = -1.0e6f * (float)padding[b * Ls + m0 + tid];
        __syncthreads();

        // ---- S = Q K^T : 4 col-tiles x 2 k-chunks ----
        f32x4 Sf[4];
#pragma unroll
        for (int t = 0; t < 4; ++t) {
            f32x4 c = (f32x4){0.f, 0.f, 0.f, 0.f};
#pragma unroll
            for (int c2 = 0; c2 < 2; ++c2) {
                short8 kf = *(short8*)&ks[t * 16 + ln16][c2 * 32 + quad * 8];
                c = __builtin_amdgcn_mfma_f32_16x16x32_bf16(qwf[c2], kf, c, 0, 0, 0);
            }
            Sf[t] = c;
        }
        // ---- Pr = Qr · band^T : 5 col-tiles, spill to per-wave LDS ----
#pragma unroll
        for (int t = 0; t < 5; ++t) {
            f32x4 c = (f32x4){0.f, 0.f, 0.f, 0.f};
#pragma unroll
            for (int c2 = 0; c2 < 2; ++c2) {
                short8 rf = *(short8*)&rband[bw + t * 16 + ln16][c2 * 32 + quad * 8];
                c = __builtin_amdgcn_mfma_f32_16x16x32_bf16(qrf[c2], rf, c, 0, 0, 0);
            }
#pragma unroll
            for (int r = 0; r < 4; ++r) prl[w][quad * 4 + r][t * 16 + ln16] = c[r];
        }
        // ---- gather pos, scale, mask ----
#pragma unroll
        for (int t = 0; t < 4; ++t) {
            const float mk = pads[t * 16 + ln16];
            f32x4 s = Sf[t];
#pragma unroll
            for (int r = 0; r < 4; ++r) {
                const int row = quad * 4 + r;
                const float pos = prl[w][row][t * 16 + ln16 - row + 15];
                s[r] = (s[r] + pos) * 0.125f + mk;
            }
            Sf[t] = s;
        }
        // ---- online softmax (rows spread over 16-lane groups) ----
        float al[4];
#pragma unroll
        for (int r = 0; r < 4; ++r) {
            float v = fmaxf(fmaxf(Sf[0][r], Sf[1][r]), fmaxf(Sf[2][r], Sf[3][r]));
#pragma unroll
            for (int off = 1; off < 16; off <<= 1) v = fmaxf(v, __shfl_xor(v, off, 64));
            const float mnew = fmaxf(m_r[r], v);
            al[r] = __expf(m_r[r] - mnew);
            m_r[r] = mnew;
        }
        float ps_[4] = {0.f, 0.f, 0.f, 0.f};
#pragma unroll
        for (int t = 0; t < 4; ++t) {
#pragma unroll
            for (int r = 0; r < 4; ++r) {
                const float p = __expf(Sf[t][r] - m_r[r]);
                ps_[r] += p;
                psm[w][quad * 4 + r][t * 16 + ln16] = f2bf(p);
            }
        }
#pragma unroll
        for (int r = 0; r < 4; ++r) {
            float v = ps_[r];
#pragma unroll
            for (int off = 1; off < 16; off <<= 1) v += __shfl_xor(v, off, 64);
            l_r[r] = l_r[r] * al[r] + v;
        }
#pragma unroll
        for (int t = 0; t < 4; ++t)
#pragma unroll
            for (int r = 0; r < 4; ++r) accO[t][r] *= al[r];

        // ---- PV : P (A-layout via LDS) x V^T col-tiles ----
        short8 pA[2];
#pragma unroll
        for (int c2 = 0; c2 < 2; ++c2)
            pA[c2] = *(short8*)&psm[w][ln16][c2 * 32 + quad * 8];
#pragma unroll
        for (int t = 0; t < 4; ++t) {
            f32x4 c = accO[t];
#pragma unroll
            for (int c2 = 0; c2 < 2; ++c2) {
                short8 vf = *(short8*)&vsT[t * 16 + ln16][c2 * 32 + quad * 8];
                c = __builtin_amdgcn_mfma_f32_16x16x32_bf16(pA[c2], vf, c, 0, 0, 0);
            }
            accO[t] = c;
        }
    }

    // ---- epilogue: normalize, store f32 ----
#pragma unroll
    for (int r = 0; r < 4; ++r) {
        const float inv = 1.f / l_r[r];
        const long row = (long)(b * Ls + l0 + w * 16 + quad * 4 + r);
        float* dst = ao + row * 1024 + n * 64;
#pragma unroll
        for (int t = 0; t < 4; ++t)
            dst[t * 16 + ln16] = accO[t][r] * inv;
    }
}

// ---------------------------------------------------------------------------
// LayerNorm in-place over rows of x (4096 x 1024)
// ---------------------------------------------------------------------------
__global__ __launch_bounds__(256) void ln_kernel(
    float* x, const float* __restrict__ g, const float* __restrict__ bb)
{
    const int row = blockIdx.x;
    const int tid = threadIdx.x;
    float4 v = ((const float4*)(x + (long)row * Dd))[tid];
    float s  = v.x + v.y + v.z + v.w;
    float sq = v.x * v.x + v.y * v.y + v.z * v.z + v.w * v.w;
#pragma unroll
    for (int off = 32; off; off >>= 1) {
        s  += __shfl_down(s, off, 64);
        sq += __shfl_down(sq, off, 64);
    }
    __shared__ float ws_s[4], ws_q[4];
    __shared__ float s_mu, s_rstd;
    const int wave = tid >> 6, lane = tid & 63;
    if (lane == 0) { ws_s[wave] = s; ws_q[wave] = sq; }
    __syncthreads();
    if (tid == 0) {
        const float ts = ws_s[0] + ws_s[1] + ws_s[2] + ws_s[3];
        const float tq = ws_q[0] + ws_q[1] + ws_q[2] + ws_q[3];
        const float mu = ts / (float)Dd;
        const float var = tq / (float)Dd - mu * mu;
        s_mu = mu;
        s_rstd = rsqrtf(var + 1e-5f);
    }
    __syncthreads();
    const float mu = s_mu, rstd = s_rstd;
    const float4 gv = ((const float4*)g)[tid];
    const float4 bv = ((const float4*)bb)[tid];
    float4 o;
    o.x = (v.x - mu) * rstd * gv.x + bv.x;
    o.y = (v.y - mu) * rstd * gv.y + bv.y;
    o.z = (v.z - mu) * rstd * gv.z + bv.z;
    o.w = (v.w - mu) * rstd * gv.w + bv.w;
    ((float4*)(x + (long)row * Dd))[tid] = o;
}

// ---------------------------------------------------------------------------
extern "C" void kernel_launch(void* const* d_in, const int* in_sizes, int n_in,
                              void* d_out, int out_size, void* d_ws, size_t ws_size,
                              hipStream_t stream) {
    const float* q      = (const float*)d_in[0];
    const float* k      = (const float*)d_in[1];
    const float* v      = (const float*)d_in[2];
    const float* posenc = (const float*)d_in[3];
    const int*   pad    = (const int*)  d_in[4];
    const float* q_w    = (const float*)d_in[5];
    const float* k_w    = (const float*)d_in[6];
    const float* k_b    = (const float*)d_in[7];
    const float* v_w    = (const float*)d_in[8];
    const float* v_b    = (const float*)d_in[9];
    const float* rwb    = (const float*)d_in[10];
    const float* rrb    = (const float*)d_in[11];
    const float* r_ker  = (const float*)d_in[12];
    const float* post_w = (const float*)d_in[13];
    const float* post_b = (const float*)d_in[14];
    const float* ln_g   = (const float*)d_in[15];
    const float* ln_b   = (const float*)d_in[16];
    float* out = (float*)d_out;

    const long M4 = (long)Bb * Ls * Nn * Hh;      // 4096*1024
    short* qh = (short*)d_ws;                     // bf16 buffers
    short* kh = qh + M4;
    short* vh = kh + M4;
    short* rS = vh + M4;                          // N*R*H shorts
    float* ao = (float*)(rS + (long)Nn * Rr * Hh);// f32 attention out (16MB)

    const dim3 blk(256);
    const int M = Bb * Ls;        // 4096
    const int NH = Nn * Hh;       // 1024

    // QKV projections -> bf16
    gemm64<<<dim3(NH / TS, M / TS, 1), blk, 0, stream>>>(
        q, Dd, 0, q_w, NH, 0, qh, NH, 0, 1, nullptr, nullptr, 0, Dd);
    gemm64<<<dim3(NH / TS, M / TS, 1), blk, 0, stream>>>(
        k, Dd, 0, k_w, NH, 0, kh, NH, 0, 1, k_b, nullptr, 0, Dd);
    gemm64<<<dim3(NH / TS, M / TS, 1), blk, 0, stream>>>(
        v, Dd, 0, v_w, NH, 0, vh, NH, 0, 1, v_b, nullptr, 0, Dd);

    // r projection -> bf16: per n, (2048 x 1024) * (1024 x 64)
    gemm64<<<dim3(1, Rr / TS, Nn), blk, 0, stream>>>(
        posenc, Dd, 0, r_ker, Hh, (long)Dd * Hh, rS, Hh, (long)Rr * Hh, 1,
        nullptr, nullptr, 0, Dd);

    // MFMA attention -> ao (f32)
    attn_mfma<<<dim3(Ls / 64, Nn, Bb), blk, 0, stream>>>(
        qh, kh, vh, rS, pad, rwb, rrb, ao);

    // Post projection + bias + residual (f32)
    gemm64<<<dim3(Dd / TS, M / TS, 1), blk, 0, stream>>>(
        ao, NH, 0, post_w, Dd, 0, out, Dd, 0, 0, post_b, q, Dd, Dd);

    // LayerNorm in-place on out
    ln_kernel<<<dim3(M), blk, 0, stream>>>(out, ln_g, ln_b);
}

// Round 4
// 405.843 us; speedup vs baseline: 3.7094x; 1.9444x over previous
//
#include <hip/hip_runtime.h>
#include <hip/hip_bf16.h>

// Problem constants
#define Bb 4
#define Ls 1024
#define Dd 1024
#define Nn 16
#define Hh 64
#define Rr 2048

typedef __attribute__((ext_vector_type(8))) short short8;
typedef __attribute__((ext_vector_type(4))) short short4v;
typedef __attribute__((ext_vector_type(4))) float f32x4;

__device__ __forceinline__ float bf2f(short s) {
    union { unsigned u; float f; } c;
    c.u = ((unsigned)(unsigned short)s) << 16;
    return c.f;
}
__device__ __forceinline__ short f2bf(float f) {
    __hip_bfloat16 h = __float2bfloat16(f);
    return *reinterpret_cast<short*>(&h);
}

// async global->LDS, 16B per lane; LDS dest = wave-uniform base + lane*16
__device__ __forceinline__ void gld16(const void* g, void* l) {
    __builtin_amdgcn_global_load_lds(
        (const __attribute__((address_space(1))) unsigned int*)g,
        (__attribute__((address_space(3))) unsigned int*)l, 16, 0, 0);
}

// ---------------------------------------------------------------------------
// Prep: batched f32 -> bf16 convert-copy (4 arrays)
// ---------------------------------------------------------------------------
struct CopyDesc {
    const float* src[4];
    short* dst[4];
    int n[4];
};

__global__ __launch_bounds__(256) void f2bf_multi(CopyDesc cd) {
    const int z = blockIdx.y;
    const int base = (blockIdx.x * 256 + threadIdx.x) * 8;
    if (base >= cd.n[z]) return;
    const float* s = cd.src[z] + base;
    const float4 a = *(const float4*)s;
    const float4 b = *(const float4*)(s + 4);
    short8 o;
    o[0] = f2bf(a.x); o[1] = f2bf(a.y); o[2] = f2bf(a.z); o[3] = f2bf(a.w);
    o[4] = f2bf(b.x); o[5] = f2bf(b.y); o[6] = f2bf(b.z); o[7] = f2bf(b.w);
    *(short8*)(cd.dst[z] + base) = o;
}

// ---------------------------------------------------------------------------
// Prep: tiled transpose f32 (R x C) -> bf16 (C x R), batched
// ---------------------------------------------------------------------------
__global__ __launch_bounds__(256) void transpose_f2bf(
    const float* __restrict__ in, short* __restrict__ out,
    int C, int R, long inStride, long outStride)
{
    in  += (long)blockIdx.z * inStride;
    out += (long)blockIdx.z * outStride;
    const int r0 = blockIdx.y * 64, c0 = blockIdx.x * 64;
    __shared__ float T[64][65];
    const int t = threadIdx.x;
    const int rr = t >> 4, c4 = (t & 15) * 4;
#pragma unroll
    for (int p = 0; p < 4; ++p) {
        const float4 v = *(const float4*)&in[(long)(r0 + p * 16 + rr) * C + c0 + c4];
        T[p * 16 + rr][c4 + 0] = v.x;
        T[p * 16 + rr][c4 + 1] = v.y;
        T[p * 16 + rr][c4 + 2] = v.z;
        T[p * 16 + rr][c4 + 3] = v.w;
    }
    __syncthreads();
#pragma unroll
    for (int p = 0; p < 4; ++p) {
        const int j = p * 16 + (t >> 4);
        const int d4 = (t & 15) * 4;
        short4v o;
#pragma unroll
        for (int u = 0; u < 4; ++u) o[u] = f2bf(T[d4 + u][j]);
        *(short4v*)&out[(long)(c0 + j) * R + r0 + d4] = o;
    }
}

__global__ void bias_init(float* dst, const float* kb, const float* vb) {
    const int i = blockIdx.x * 256 + threadIdx.x;
    if (i >= 3072) return;
    dst[i] = (i < 1024) ? 0.f : (i < 2048 ? kb[i - 1024] : vb[i - 2048]);
}

// ---------------------------------------------------------------------------
// MFMA GEMM (m97 structure): C[M x N'] = A[M x K] * Bt[N' x K]^T
// 128x128 tile, BK=32, 256 threads (4 waves, each 64x64), global_load_lds.
// ---------------------------------------------------------------------------
__global__ __launch_bounds__(256) void gemm_bt(
    const short* __restrict__ A, int lda, long aStride,
    const short* __restrict__ Bt, int ldb, long bStride,
    const float* __restrict__ bias, long biasStride,
    const float* __restrict__ residual, int ldr,
    void* __restrict__ Cv, int ldc, long cStride, int out_bf16, int K)
{
    const int z = blockIdx.z;
    A  += (long)z * aStride;
    Bt += (long)z * bStride;

    const int row0 = blockIdx.y * 128;
    const int col0 = blockIdx.x * 128;

    __shared__ short As[128 * 32];
    __shared__ short Bs[128 * 32];

    const int tid  = threadIdx.x;
    const int w    = tid >> 6;
    const int lane = tid & 63;
    const int quad = lane >> 4;
    const int ln16 = lane & 15;
    const int wr   = (w >> 1) * 64;
    const int wc   = (w & 1) * 64;

    f32x4 acc[4][4];
#pragma unroll
    for (int a = 0; a < 4; ++a)
#pragma unroll
        for (int b = 0; b < 4; ++b) acc[a][b] = (f32x4){0.f, 0.f, 0.f, 0.f};

    // staging addresses: row = p*64 + w*16 + lane/4, col = (lane&3)*8 shorts
    const int srow = w * 16 + (lane >> 2);
    const int scol = (lane & 3) * 8;
    const short* gA = A  + (long)(row0 + srow) * lda + scol;
    const short* gB = Bt + (long)(col0 + srow) * ldb + scol;
    short* lA0 = As + w * 512;
    short* lB0 = Bs + w * 512;

    for (int k0 = 0; k0 < K; k0 += 32) {
        __syncthreads();
        gld16(gA + k0,                 lA0);
        gld16(gA + k0 + (long)64 * lda, lA0 + 2048);
        gld16(gB + k0,                 lB0);
        gld16(gB + k0 + (long)64 * ldb, lB0 + 2048);
        __syncthreads();

        short8 af[4], bfr[4];
#pragma unroll
        for (int tm = 0; tm < 4; ++tm)
            af[tm] = *(const short8*)&As[(wr + tm * 16 + ln16) * 32 + quad * 8];
#pragma unroll
        for (int tn = 0; tn < 4; ++tn)
            bfr[tn] = *(const short8*)&Bs[(wc + tn * 16 + ln16) * 32 + quad * 8];
#pragma unroll
        for (int tm = 0; tm < 4; ++tm)
#pragma unroll
            for (int tn = 0; tn < 4; ++tn)
                acc[tm][tn] = __builtin_amdgcn_mfma_f32_16x16x32_bf16(
                    af[tm], bfr[tn], acc[tm][tn], 0, 0, 0);
    }

    // epilogue
    float bv[4];
#pragma unroll
    for (int tn = 0; tn < 4; ++tn)
        bv[tn] = bias ? bias[z * biasStride + col0 + wc + tn * 16 + ln16] : 0.f;

    short* Cb = (short*)Cv + (long)z * cStride;
    float* Cf = (float*)Cv + (long)z * cStride;
#pragma unroll
    for (int tm = 0; tm < 4; ++tm) {
#pragma unroll
        for (int r = 0; r < 4; ++r) {
            const long row = row0 + wr + tm * 16 + quad * 4 + r;
#pragma unroll
            for (int tn = 0; tn < 4; ++tn) {
                const int col = col0 + wc + tn * 16 + ln16;
                float val = acc[tm][tn][r] + bv[tn];
                if (residual) val += residual[row * (long)ldr + col];
                if (out_bf16) Cb[row * (long)ldc + col] = f2bf(val);
                else          Cf[row * (long)ldc + col] = val;
            }
        }
    }
}

// ---------------------------------------------------------------------------
// MFMA attention. Block = 4 waves; 64 queries/block, 64-key tiles.
// rS layout: [r][(n,h)] (2048 x 1024). Output ao bf16.
// ---------------------------------------------------------------------------
__global__ __launch_bounds__(256) void attn_mfma(
    const short* __restrict__ qh, const short* __restrict__ kh,
    const short* __restrict__ vh, const short* __restrict__ rS,
    const int* __restrict__ padding, const float* __restrict__ rwb,
    const float* __restrict__ rrb, short* __restrict__ ao)
{
    const int lt = blockIdx.x, n = blockIdx.y, b = blockIdx.z;
    const int l0 = lt * 64;
    const int tid  = threadIdx.x;
    const int w    = tid >> 6;
    const int lane = tid & 63;
    const int quad = lane >> 4;
    const int ln16 = lane & 15;

    __shared__ short ks[64][72];
    __shared__ short vsT[64][72];
    __shared__ short rband[128][72];
    __shared__ float prl[4][16][83];
    __shared__ short psm[4][16][72];
    __shared__ float pads[64];

    short8 qwf[2], qrf[2];
    {
        const long rowoff = ((long)(b * Ls + l0 + w * 16 + ln16)) * (Nn * Hh) + n * Hh;
#pragma unroll
        for (int c = 0; c < 2; ++c) {
            const int kb = c * 32 + quad * 8;
            short8 qv = *(const short8*)(qh + rowoff + kb);
#pragma unroll
            for (int j = 0; j < 8; ++j) {
                float qf = bf2f(qv[j]);
                qwf[c][j] = f2bf(qf + rwb[n * Hh + kb + j]);
                qrf[c][j] = f2bf(qf + rrb[n * Hh + kb + j]);
            }
        }
    }

    float m_r[4], l_r[4];
    f32x4 accO[4];
#pragma unroll
    for (int r = 0; r < 4; ++r) { m_r[r] = -INFINITY; l_r[r] = 0.f; }
#pragma unroll
    for (int t = 0; t < 4; ++t) accO[t] = (f32x4){0.f, 0.f, 0.f, 0.f};

    const int bw = 48 - 16 * w;

    for (int mt = 0; mt < Ls / 64; ++mt) {
        const int m0 = mt * 64;
        __syncthreads();

#pragma unroll
        for (int p = 0; p < 2; ++p) {
            int idx = tid + p * 256;
            int r_ = idx >> 3, cq = (idx & 7) * 8;
            *(short8*)&ks[r_][cq] =
                *(const short8*)(kh + ((long)(b * Ls + m0 + r_)) * 1024 + n * 64 + cq);
        }
        {
            int kp = tid & 31, cq = (tid >> 5) * 8;
            const short* vp = vh + ((long)(b * Ls + m0 + 2 * kp)) * 1024 + n * 64 + cq;
            short8 va = *(const short8*)vp;
            short8 vb2 = *(const short8*)(vp + 1024);
#pragma unroll
            for (int u = 0; u < 8; ++u) {
                unsigned pk = ((unsigned)(unsigned short)va[u]) |
                              (((unsigned)(unsigned short)vb2[u]) << 16);
                *(unsigned*)&vsT[cq + u][2 * kp] = pk;
            }
        }
        {
            const int cb = 961 - l0 + m0;
#pragma unroll
            for (int p = 0; p < 4; ++p) {
                int idx = tid + p * 256;
                int r_ = idx >> 3, cq = (idx & 7) * 8;
                if (r_ < 127) {
                    *(short8*)&rband[r_][cq] =
                        *(const short8*)(rS + (long)(cb + r_) * 1024 + n * 64 + cq);
                } else {
                    *(short8*)&rband[r_][cq] = (short8)0;
                }
            }
        }
        if (tid < 64) pads[tid] = -1.0e6f * (float)padding[b * Ls + m0 + tid];
        __syncthreads();

        f32x4 Sf[4];
#pragma unroll
        for (int t = 0; t < 4; ++t) {
            f32x4 c = (f32x4){0.f, 0.f, 0.f, 0.f};
#pragma unroll
            for (int c2 = 0; c2 < 2; ++c2) {
                short8 kf = *(short8*)&ks[t * 16 + ln16][c2 * 32 + quad * 8];
                c = __builtin_amdgcn_mfma_f32_16x16x32_bf16(qwf[c2], kf, c, 0, 0, 0);
            }
            Sf[t] = c;
        }
#pragma unroll
        for (int t = 0; t < 5; ++t) {
            f32x4 c = (f32x4){0.f, 0.f, 0.f, 0.f};
#pragma unroll
            for (int c2 = 0; c2 < 2; ++c2) {
                short8 rf = *(short8*)&rband[bw + t * 16 + ln16][c2 * 32 + quad * 8];
                c = __builtin_amdgcn_mfma_f32_16x16x32_bf16(qrf[c2], rf, c, 0, 0, 0);
            }
#pragma unroll
            for (int r = 0; r < 4; ++r) prl[w][quad * 4 + r][t * 16 + ln16] = c[r];
        }
#pragma unroll
        for (int t = 0; t < 4; ++t) {
            const float mk = pads[t * 16 + ln16];
            f32x4 s = Sf[t];
#pragma unroll
            for (int r = 0; r < 4; ++r) {
                const int row = quad * 4 + r;
                const float pos = prl[w][row][t * 16 + ln16 - row + 15];
                s[r] = (s[r] + pos) * 0.125f + mk;
            }
            Sf[t] = s;
        }
        float al[4];
#pragma unroll
        for (int r = 0; r < 4; ++r) {
            float v = fmaxf(fmaxf(Sf[0][r], Sf[1][r]), fmaxf(Sf[2][r], Sf[3][r]));
#pragma unroll
            for (int off = 1; off < 16; off <<= 1) v = fmaxf(v, __shfl_xor(v, off, 64));
            const float mnew = fmaxf(m_r[r], v);
            al[r] = __expf(m_r[r] - mnew);
            m_r[r] = mnew;
        }
        float ps_[4] = {0.f, 0.f, 0.f, 0.f};
#pragma unroll
        for (int t = 0; t < 4; ++t) {
#pragma unroll
            for (int r = 0; r < 4; ++r) {
                const float p = __expf(Sf[t][r] - m_r[r]);
                ps_[r] += p;
                psm[w][quad * 4 + r][t * 16 + ln16] = f2bf(p);
            }
        }
#pragma unroll
        for (int r = 0; r < 4; ++r) {
            float v = ps_[r];
#pragma unroll
            for (int off = 1; off < 16; off <<= 1) v += __shfl_xor(v, off, 64);
            l_r[r] = l_r[r] * al[r] + v;
        }
#pragma unroll
        for (int t = 0; t < 4; ++t)
#pragma unroll
            for (int r = 0; r < 4; ++r) accO[t][r] *= al[r];

        short8 pA[2];
#pragma unroll
        for (int c2 = 0; c2 < 2; ++c2)
            pA[c2] = *(short8*)&psm[w][ln16][c2 * 32 + quad * 8];
#pragma unroll
        for (int t = 0; t < 4; ++t) {
            f32x4 c = accO[t];
#pragma unroll
            for (int c2 = 0; c2 < 2; ++c2) {
                short8 vf = *(short8*)&vsT[t * 16 + ln16][c2 * 32 + quad * 8];
                c = __builtin_amdgcn_mfma_f32_16x16x32_bf16(pA[c2], vf, c, 0, 0, 0);
            }
            accO[t] = c;
        }
    }

#pragma unroll
    for (int r = 0; r < 4; ++r) {
        const float inv = 1.f / l_r[r];
        const long row = (long)(b * Ls + l0 + w * 16 + quad * 4 + r);
        short* dst = ao + row * 1024 + n * 64;
#pragma unroll
        for (int t = 0; t < 4; ++t)
            dst[t * 16 + ln16] = f2bf(accO[t][r] * inv);
    }
}

// ---------------------------------------------------------------------------
// LayerNorm in-place over rows of x (4096 x 1024)
// ---------------------------------------------------------------------------
__global__ __launch_bounds__(256) void ln_kernel(
    float* x, const float* __restrict__ g, const float* __restrict__ bb)
{
    const int row = blockIdx.x;
    const int tid = threadIdx.x;
    float4 v = ((const float4*)(x + (long)row * Dd))[tid];
    float s  = v.x + v.y + v.z + v.w;
    float sq = v.x * v.x + v.y * v.y + v.z * v.z + v.w * v.w;
#pragma unroll
    for (int off = 32; off; off >>= 1) {
        s  += __shfl_down(s, off, 64);
        sq += __shfl_down(sq, off, 64);
    }
    __shared__ float ws_s[4], ws_q[4];
    __shared__ float s_mu, s_rstd;
    const int wave = tid >> 6, lane = tid & 63;
    if (lane == 0) { ws_s[wave] = s; ws_q[wave] = sq; }
    __syncthreads();
    if (tid == 0) {
        const float ts = ws_s[0] + ws_s[1] + ws_s[2] + ws_s[3];
        const float tq = ws_q[0] + ws_q[1] + ws_q[2] + ws_q[3];
        const float mu = ts / (float)Dd;
        const float var = tq / (float)Dd - mu * mu;
        s_mu = mu;
        s_rstd = rsqrtf(var + 1e-5f);
    }
    __syncthreads();
    const float mu = s_mu, rstd = s_rstd;
    const float4 gv = ((const float4*)g)[tid];
    const float4 bv = ((const float4*)bb)[tid];
    float4 o;
    o.x = (v.x - mu) * rstd * gv.x + bv.x;
    o.y = (v.y - mu) * rstd * gv.y + bv.y;
    o.z = (v.z - mu) * rstd * gv.z + bv.z;
    o.w = (v.w - mu) * rstd * gv.w + bv.w;
    ((float4*)(x + (long)row * Dd))[tid] = o;
}

// ---------------------------------------------------------------------------
extern "C" void kernel_launch(void* const* d_in, const int* in_sizes, int n_in,
                              void* d_out, int out_size, void* d_ws, size_t ws_size,
                              hipStream_t stream) {
    const float* q      = (const float*)d_in[0];
    const float* k      = (const float*)d_in[1];
    const float* v      = (const float*)d_in[2];
    const float* posenc = (const float*)d_in[3];
    const int*   pad    = (const int*)  d_in[4];
    const float* q_w    = (const float*)d_in[5];
    const float* k_w    = (const float*)d_in[6];
    const float* k_b    = (const float*)d_in[7];
    const float* v_w    = (const float*)d_in[8];
    const float* v_b    = (const float*)d_in[9];
    const float* rwb    = (const float*)d_in[10];
    const float* rrb    = (const float*)d_in[11];
    const float* r_ker  = (const float*)d_in[12];
    const float* post_w = (const float*)d_in[13];
    const float* post_b = (const float*)d_in[14];
    const float* ln_g   = (const float*)d_in[15];
    const float* ln_b   = (const float*)d_in[16];
    float* out = (float*)d_out;

    const long M1 = 1L << 20;                 // 1M elements
    short* ws = (short*)d_ws;
    short* xq   = ws;                         // 4M (aliased by ao later)
    short* xk   = ws + 4 * M1;                // 4M
    short* xv   = ws + 8 * M1;                // 4M
    short* pe   = ws + 12 * M1;               // 2M
    short* wT   = ws + 14 * M1;               // 3M (qwT,kwT,vwT)
    short* rkT  = ws + 17 * M1;               // 1M
    short* pwT  = ws + 18 * M1;               // 1M
    short* qh   = ws + 19 * M1;               // 4M
    short* kh   = ws + 23 * M1;               // 4M
    short* vh   = ws + 27 * M1;               // 4M
    short* rS   = ws + 31 * M1;               // 2M
    float* bqkv = (float*)(ws + 33 * M1);     // 3072 f32
    short* ao   = xq;                          // alias: xq dead after QKV GEMM

    const dim3 blk(256);

    // ---- prep: convert copies (post_w now handled by transpose below) ----
    CopyDesc cd;
    cd.src[0] = q;      cd.dst[0] = xq;  cd.n[0] = 4 * (int)M1;
    cd.src[1] = k;      cd.dst[1] = xk;  cd.n[1] = 4 * (int)M1;
    cd.src[2] = v;      cd.dst[2] = xv;  cd.n[2] = 4 * (int)M1;
    cd.src[3] = posenc; cd.dst[3] = pe;  cd.n[3] = 2 * (int)M1;
    f2bf_multi<<<dim3(2048, 4), blk, 0, stream>>>(cd);

    // ---- prep: weight transposes -> B^T form ----
    transpose_f2bf<<<dim3(16, 16, 1), blk, 0, stream>>>(q_w, wT,          1024, 1024, 0, 0);
    transpose_f2bf<<<dim3(16, 16, 1), blk, 0, stream>>>(k_w, wT + M1,     1024, 1024, 0, 0);
    transpose_f2bf<<<dim3(16, 16, 1), blk, 0, stream>>>(v_w, wT + 2 * M1, 1024, 1024, 0, 0);
    // post_w (NH x D) -> pwT (D x NH): Bt[d][(n,h)] = post_w[(n,h)][d]
    transpose_f2bf<<<dim3(16, 16, 1), blk, 0, stream>>>(post_w, pwT,      1024, 1024, 0, 0);
    transpose_f2bf<<<dim3(1, 16, 16), blk, 0, stream>>>(r_ker, rkT, 64, 1024,
                                                        (long)1024 * 64, (long)64 * 1024);
    bias_init<<<dim3(12), blk, 0, stream>>>(bqkv, k_b, v_b);

    // ---- QKV projections (batched z=3): (4096x1024)x(1024x1024) -> bf16 ----
    gemm_bt<<<dim3(8, 32, 3), blk, 0, stream>>>(
        xq, 1024, 4 * M1, wT, 1024, M1, bqkv, 1024,
        nullptr, 0, qh, 1024, 4 * M1, 1, 1024);

    // ---- r projection: (2048x1024)x(1024x1024) -> rS bf16 [r][(n,h)] ----
    gemm_bt<<<dim3(8, 16, 1), blk, 0, stream>>>(
        pe, 1024, 0, rkT, 1024, 0, nullptr, 0,
        nullptr, 0, rS, 1024, 0, 1, 1024);

    // ---- attention -> ao bf16 ----
    attn_mfma<<<dim3(Ls / 64, Nn, Bb), blk, 0, stream>>>(
        qh, kh, vh, rS, pad, rwb, rrb, ao);

    // ---- post projection + bias + residual -> f32 out ----
    gemm_bt<<<dim3(8, 32, 1), blk, 0, stream>>>(
        ao, 1024, 0, pwT, 1024, 0, post_b, 0,
        q, 1024, out, 1024, 0, 0, 1024);

    // ---- LayerNorm in-place ----
    ln_kernel<<<dim3(Bb * Ls), blk, 0, stream>>>(out, ln_g, ln_b);
}

// Round 5
// 354.280 us; speedup vs baseline: 4.2493x; 1.1455x over previous
//
#include <hip/hip_runtime.h>
#include <hip/hip_bf16.h>

// Problem constants
#define Bb 4
#define Ls 1024
#define Dd 1024
#define Nn 16
#define Hh 64
#define Rr 2048

typedef __attribute__((ext_vector_type(8))) short short8;
typedef __attribute__((ext_vector_type(4))) short short4v;
typedef __attribute__((ext_vector_type(4))) float f32x4;

__device__ __forceinline__ float bf2f(short s) {
    union { unsigned u; float f; } c;
    c.u = ((unsigned)(unsigned short)s) << 16;
    return c.f;
}
__device__ __forceinline__ short f2bf(float f) {
    __hip_bfloat16 h = __float2bfloat16(f);
    return *reinterpret_cast<short*>(&h);
}

// async global->LDS, 16B per lane; LDS dest = wave-uniform base + lane*16
__device__ __forceinline__ void gld16(const void* g, void* l) {
    __builtin_amdgcn_global_load_lds(
        (const __attribute__((address_space(1))) unsigned int*)g,
        (__attribute__((address_space(3))) unsigned int*)l, 16, 0, 0);
}

// ---------------------------------------------------------------------------
// Prep: batched f32 -> bf16 convert-copy (4 arrays)
// ---------------------------------------------------------------------------
struct CopyDesc {
    const float* src[4];
    short* dst[4];
    int n[4];
};

__global__ __launch_bounds__(256) void f2bf_multi(CopyDesc cd) {
    const int z = blockIdx.y;
    const int base = (blockIdx.x * 256 + threadIdx.x) * 8;
    if (base >= cd.n[z]) return;
    const float* s = cd.src[z] + base;
    const float4 a = *(const float4*)s;
    const float4 b = *(const float4*)(s + 4);
    short8 o;
    o[0] = f2bf(a.x); o[1] = f2bf(a.y); o[2] = f2bf(a.z); o[3] = f2bf(a.w);
    o[4] = f2bf(b.x); o[5] = f2bf(b.y); o[6] = f2bf(b.z); o[7] = f2bf(b.w);
    *(short8*)(cd.dst[z] + base) = o;
}

// ---------------------------------------------------------------------------
// Prep: batched tiled transpose of four 1024x1024 f32 -> bf16 (transposed)
// ---------------------------------------------------------------------------
struct TransDesc {
    const float* src[4];
    short* dst[4];
};

__global__ __launch_bounds__(256) void transpose4_f2bf(TransDesc td) {
    const float* in = td.src[blockIdx.z];
    short* out = td.dst[blockIdx.z];
    const int r0 = blockIdx.y * 64, c0 = blockIdx.x * 64;
    __shared__ float T[64][65];
    const int t = threadIdx.x;
    const int rr = t >> 4, c4 = (t & 15) * 4;
#pragma unroll
    for (int p = 0; p < 4; ++p) {
        const float4 v = *(const float4*)&in[(long)(r0 + p * 16 + rr) * 1024 + c0 + c4];
        T[p * 16 + rr][c4 + 0] = v.x;
        T[p * 16 + rr][c4 + 1] = v.y;
        T[p * 16 + rr][c4 + 2] = v.z;
        T[p * 16 + rr][c4 + 3] = v.w;
    }
    __syncthreads();
#pragma unroll
    for (int p = 0; p < 4; ++p) {
        const int j = p * 16 + (t >> 4);
        const int d4 = (t & 15) * 4;
        short4v o;
#pragma unroll
        for (int u = 0; u < 4; ++u) o[u] = f2bf(T[d4 + u][j]);
        *(short4v*)&out[(long)(c0 + j) * 1024 + r0 + d4] = o;
    }
}

// ---------------------------------------------------------------------------
// Prep: tiled transpose f32 (R x C) -> bf16 (C x R), batched (for r_kernel)
// ---------------------------------------------------------------------------
__global__ __launch_bounds__(256) void transpose_f2bf(
    const float* __restrict__ in, short* __restrict__ out,
    int C, int R, long inStride, long outStride)
{
    in  += (long)blockIdx.z * inStride;
    out += (long)blockIdx.z * outStride;
    const int r0 = blockIdx.y * 64, c0 = blockIdx.x * 64;
    __shared__ float T[64][65];
    const int t = threadIdx.x;
    const int rr = t >> 4, c4 = (t & 15) * 4;
#pragma unroll
    for (int p = 0; p < 4; ++p) {
        const float4 v = *(const float4*)&in[(long)(r0 + p * 16 + rr) * C + c0 + c4];
        T[p * 16 + rr][c4 + 0] = v.x;
        T[p * 16 + rr][c4 + 1] = v.y;
        T[p * 16 + rr][c4 + 2] = v.z;
        T[p * 16 + rr][c4 + 3] = v.w;
    }
    __syncthreads();
#pragma unroll
    for (int p = 0; p < 4; ++p) {
        const int j = p * 16 + (t >> 4);
        const int d4 = (t & 15) * 4;
        short4v o;
#pragma unroll
        for (int u = 0; u < 4; ++u) o[u] = f2bf(T[d4 + u][j]);
        *(short4v*)&out[(long)(c0 + j) * R + r0 + d4] = o;
    }
}

// bias vector for merged QKV+r GEMM: [0 | k_b | v_b | 0], 4096 floats
__global__ void bias_init(float* dst, const float* kb, const float* vb) {
    const int i = blockIdx.x * 256 + threadIdx.x;
    if (i >= 4096) return;
    float v = 0.f;
    if (i >= 1024 && i < 2048) v = kb[i - 1024];
    else if (i >= 2048 && i < 3072) v = vb[i - 2048];
    dst[i] = v;
}

// ---------------------------------------------------------------------------
// MFMA GEMM (m97 structure): C[M x N'] = A[M x K] * Bt[N' x K]^T
// 128x128 tile, BK=32, 256 threads (4 waves, each 64x64), global_load_lds.
// z=3 may have fewer rows (y3cut row-tiles).
// ---------------------------------------------------------------------------
__global__ __launch_bounds__(256) void gemm_bt(
    const short* __restrict__ A, int lda, long aStride,
    const short* __restrict__ Bt, int ldb, long bStride,
    const float* __restrict__ bias, long biasStride,
    const float* __restrict__ residual, int ldr,
    void* __restrict__ Cv, int ldc, long cStride, int out_bf16, int K, int y3cut)
{
    const int z = blockIdx.z;
    if (z == 3 && (int)blockIdx.y >= y3cut) return;
    A  += (long)z * aStride;
    Bt += (long)z * bStride;

    const int row0 = blockIdx.y * 128;
    const int col0 = blockIdx.x * 128;

    __shared__ short As[128 * 32];
    __shared__ short Bs[128 * 32];

    const int tid  = threadIdx.x;
    const int w    = tid >> 6;
    const int lane = tid & 63;
    const int quad = lane >> 4;
    const int ln16 = lane & 15;
    const int wr   = (w >> 1) * 64;
    const int wc   = (w & 1) * 64;

    f32x4 acc[4][4];
#pragma unroll
    for (int a = 0; a < 4; ++a)
#pragma unroll
        for (int b = 0; b < 4; ++b) acc[a][b] = (f32x4){0.f, 0.f, 0.f, 0.f};

    const int srow = w * 16 + (lane >> 2);
    const int scol = (lane & 3) * 8;
    const short* gA = A  + (long)(row0 + srow) * lda + scol;
    const short* gB = Bt + (long)(col0 + srow) * ldb + scol;
    short* lA0 = As + w * 512;
    short* lB0 = Bs + w * 512;

    for (int k0 = 0; k0 < K; k0 += 32) {
        __syncthreads();
        gld16(gA + k0,                  lA0);
        gld16(gA + k0 + (long)64 * lda, lA0 + 2048);
        gld16(gB + k0,                  lB0);
        gld16(gB + k0 + (long)64 * ldb, lB0 + 2048);
        __syncthreads();

        short8 af[4], bfr[4];
#pragma unroll
        for (int tm = 0; tm < 4; ++tm)
            af[tm] = *(const short8*)&As[(wr + tm * 16 + ln16) * 32 + quad * 8];
#pragma unroll
        for (int tn = 0; tn < 4; ++tn)
            bfr[tn] = *(const short8*)&Bs[(wc + tn * 16 + ln16) * 32 + quad * 8];
#pragma unroll
        for (int tm = 0; tm < 4; ++tm)
#pragma unroll
            for (int tn = 0; tn < 4; ++tn)
                acc[tm][tn] = __builtin_amdgcn_mfma_f32_16x16x32_bf16(
                    af[tm], bfr[tn], acc[tm][tn], 0, 0, 0);
    }

    float bv[4];
#pragma unroll
    for (int tn = 0; tn < 4; ++tn)
        bv[tn] = bias ? bias[z * biasStride + col0 + wc + tn * 16 + ln16] : 0.f;

    short* Cb = (short*)Cv + (long)z * cStride;
    float* Cf = (float*)Cv + (long)z * cStride;
#pragma unroll
    for (int tm = 0; tm < 4; ++tm) {
#pragma unroll
        for (int r = 0; r < 4; ++r) {
            const long row = row0 + wr + tm * 16 + quad * 4 + r;
#pragma unroll
            for (int tn = 0; tn < 4; ++tn) {
                const int col = col0 + wc + tn * 16 + ln16;
                float val = acc[tm][tn][r] + bv[tn];
                if (residual) val += residual[row * (long)ldr + col];
                if (out_bf16) Cb[row * (long)ldc + col] = f2bf(val);
                else          Cf[row * (long)ldc + col] = val;
            }
        }
    }
}

// ---------------------------------------------------------------------------
// MFMA attention. Block = 4 waves; 64 queries/block, 64-key tiles.
// rS layout: [r][(n,h)] (2048 x 1024). Output ao bf16.
// Pr skew gather via in-quad shuffles (no LDS spill); circular r-band (&127).
// ---------------------------------------------------------------------------
__global__ __launch_bounds__(256, 3) void attn_mfma(
    const short* __restrict__ qh, const short* __restrict__ kh,
    const short* __restrict__ vh, const short* __restrict__ rS,
    const int* __restrict__ padding, const float* __restrict__ rwb,
    const float* __restrict__ rrb, short* __restrict__ ao)
{
    const int lt = blockIdx.x, n = blockIdx.y, b = blockIdx.z;
    const int l0 = lt * 64;
    const int tid  = threadIdx.x;
    const int w    = tid >> 6;
    const int lane = tid & 63;
    const int quad = lane >> 4;
    const int ln16 = lane & 15;

    __shared__ __align__(16) short ks[64][72];
    __shared__ __align__(16) short vsT[64][72];
    __shared__ __align__(16) short rband[128][72];   // circular: slot = row & 127
    __shared__ __align__(16) short psm[4][16][72];
    __shared__ float pads[64];

    // Q fragments (A-layout), biased two ways, loaded once
    short8 qwf[2], qrf[2];
    {
        const long rowoff = ((long)(b * Ls + l0 + w * 16 + ln16)) * (Nn * Hh) + n * Hh;
#pragma unroll
        for (int c = 0; c < 2; ++c) {
            const int kb = c * 32 + quad * 8;
            short8 qv = *(const short8*)(qh + rowoff + kb);
#pragma unroll
            for (int j = 0; j < 8; ++j) {
                float qf = bf2f(qv[j]);
                qwf[c][j] = f2bf(qf + rwb[n * Hh + kb + j]);
                qrf[c][j] = f2bf(qf + rrb[n * Hh + kb + j]);
            }
        }
    }

    float m_r[4], l_r[4];
    f32x4 accO[4];
#pragma unroll
    for (int r = 0; r < 4; ++r) { m_r[r] = -INFINITY; l_r[r] = 0.f; }
#pragma unroll
    for (int t = 0; t < 4; ++t) accO[t] = (f32x4){0.f, 0.f, 0.f, 0.f};

    const int bw  = 48 - 16 * w;     // wave's band base offset
    const int cb0 = 961 - l0;        // first band row, in [1, 961]

    for (int mt = 0; mt < Ls / 64; ++mt) {
        const int m0 = mt * 64;
        const int cb = cb0 + m0;
        __syncthreads();

        // ---- stage K tile ----
#pragma unroll
        for (int p = 0; p < 2; ++p) {
            int idx = tid + p * 256;
            int r_ = idx >> 3, cq = (idx & 7) * 8;
            *(short8*)&ks[r_][cq] =
                *(const short8*)(kh + ((long)(b * Ls + m0 + r_)) * 1024 + n * 64 + cq);
        }
        // ---- stage V transposed (paired keys -> dword stores) ----
        {
            int kp = tid & 31, cq = (tid >> 5) * 8;
            const short* vp = vh + ((long)(b * Ls + m0 + 2 * kp)) * 1024 + n * 64 + cq;
            short8 va = *(const short8*)vp;
            short8 vb2 = *(const short8*)(vp + 1024);
#pragma unroll
            for (int u = 0; u < 8; ++u) {
                unsigned pk = ((unsigned)(unsigned short)va[u]) |
                              (((unsigned)(unsigned short)vb2[u]) << 16);
                *(unsigned*)&vsT[cq + u][2 * kp] = pk;
            }
        }
        // ---- stage r band (circular) ----
        if (mt == 0) {
            // fill all 128 slots: rows cb0 .. cb0+127 (max 1088, in range)
#pragma unroll
            for (int p = 0; p < 4; ++p) {
                int idx = tid + p * 256;
                int i = idx >> 3, cq = (idx & 7) * 8;
                int g = cb0 + i;
                *(short8*)&rband[g & 127][cq] =
                    *(const short8*)(rS + (long)g * 1024 + n * 64 + cq);
            }
        } else {
            // 64 new rows: cb+63 .. cb+126 (max 2047, in range)
#pragma unroll
            for (int p = 0; p < 2; ++p) {
                int idx = tid + p * 256;
                int i = idx >> 3, cq = (idx & 7) * 8;
                int g = cb + 63 + i;
                *(short8*)&rband[g & 127][cq] =
                    *(const short8*)(rS + (long)g * 1024 + n * 64 + cq);
            }
        }
        if (tid < 64) pads[tid] = -1.0e6f * (float)padding[b * Ls + m0 + tid];
        __syncthreads();

        // ---- S = Q K^T : 4 col-tiles x 2 k-chunks ----
        f32x4 Sf[4];
#pragma unroll
        for (int t = 0; t < 4; ++t) {
            f32x4 c = (f32x4){0.f, 0.f, 0.f, 0.f};
#pragma unroll
            for (int c2 = 0; c2 < 2; ++c2) {
                short8 kf = *(short8*)&ks[t * 16 + ln16][c2 * 32 + quad * 8];
                c = __builtin_amdgcn_mfma_f32_16x16x32_bf16(qwf[c2], kf, c, 0, 0, 0);
            }
            Sf[t] = c;
        }
        // ---- Pr = Qr · band^T : 5 col-tiles, kept in registers ----
        f32x4 Prf[5];
#pragma unroll
        for (int t = 0; t < 5; ++t) {
            const short* rrow = rband[(cb + bw + t * 16 + ln16) & 127];
            f32x4 c = (f32x4){0.f, 0.f, 0.f, 0.f};
            c = __builtin_amdgcn_mfma_f32_16x16x32_bf16(
                qrf[0], *(const short8*)&rrow[quad * 8], c, 0, 0, 0);
            c = __builtin_amdgcn_mfma_f32_16x16x32_bf16(
                qrf[1], *(const short8*)&rrow[32 + quad * 8], c, 0, 0, 0);
            Prf[t] = c;
        }
        // ---- skew gather via in-quad shuffle, scale, mask ----
        // pos(row, t*16+ln16) = Pr(row, u + t*16), u = ln16-row+15 in [0,30];
        // source element lives in lane quad*16+(u&15), C-reg r, tile t+(u>=16).
#pragma unroll
        for (int r = 0; r < 4; ++r) {
            const int row = quad * 4 + r;
            const int u = ln16 - row + 15;
            const int srcLane = (quad << 4) | (u & 15);
            const float s0 = __shfl(Prf[0][r], srcLane, 64);
            const float s1 = __shfl(Prf[1][r], srcLane, 64);
            const float s2 = __shfl(Prf[2][r], srcLane, 64);
            const float s3 = __shfl(Prf[3][r], srcLane, 64);
            const float s4 = __shfl(Prf[4][r], srcLane, 64);
            const bool hi = (u >= 16);
            Sf[0][r] = (Sf[0][r] + (hi ? s1 : s0)) * 0.125f + pads[ln16];
            Sf[1][r] = (Sf[1][r] + (hi ? s2 : s1)) * 0.125f + pads[16 + ln16];
            Sf[2][r] = (Sf[2][r] + (hi ? s3 : s2)) * 0.125f + pads[32 + ln16];
            Sf[3][r] = (Sf[3][r] + (hi ? s4 : s3)) * 0.125f + pads[48 + ln16];
        }
        // ---- online softmax (rows spread over 16-lane groups) ----
        float al[4];
#pragma unroll
        for (int r = 0; r < 4; ++r) {
            float v = fmaxf(fmaxf(Sf[0][r], Sf[1][r]), fmaxf(Sf[2][r], Sf[3][r]));
#pragma unroll
            for (int off = 1; off < 16; off <<= 1) v = fmaxf(v, __shfl_xor(v, off, 64));
            const float mnew = fmaxf(m_r[r], v);
            al[r] = __expf(m_r[r] - mnew);
            m_r[r] = mnew;
        }
        float ps_[4] = {0.f, 0.f, 0.f, 0.f};
#pragma unroll
        for (int t = 0; t < 4; ++t) {
#pragma unroll
            for (int r = 0; r < 4; ++r) {
                const float p = __expf(Sf[t][r] - m_r[r]);
                ps_[r] += p;
                psm[w][quad * 4 + r][t * 16 + ln16] = f2bf(p);
            }
        }
#pragma unroll
        for (int r = 0; r < 4; ++r) {
            float v = ps_[r];
#pragma unroll
            for (int off = 1; off < 16; off <<= 1) v += __shfl_xor(v, off, 64);
            l_r[r] = l_r[r] * al[r] + v;
        }
#pragma unroll
        for (int t = 0; t < 4; ++t)
#pragma unroll
            for (int r = 0; r < 4; ++r) accO[t][r] *= al[r];

        // ---- PV : P (A-layout via per-wave LDS) x V^T col-tiles ----
        short8 pA[2];
#pragma unroll
        for (int c2 = 0; c2 < 2; ++c2)
            pA[c2] = *(short8*)&psm[w][ln16][c2 * 32 + quad * 8];
#pragma unroll
        for (int t = 0; t < 4; ++t) {
            f32x4 c = accO[t];
#pragma unroll
            for (int c2 = 0; c2 < 2; ++c2) {
                short8 vf = *(short8*)&vsT[t * 16 + ln16][c2 * 32 + quad * 8];
                c = __builtin_amdgcn_mfma_f32_16x16x32_bf16(pA[c2], vf, c, 0, 0, 0);
            }
            accO[t] = c;
        }
    }

    // ---- epilogue: normalize into per-wave psm, then coalesced bf16 store ----
#pragma unroll
    for (int t = 0; t < 4; ++t)
#pragma unroll
        for (int r = 0; r < 4; ++r)
            psm[w][quad * 4 + r][t * 16 + ln16] = f2bf(accO[t][r] / l_r[(unsigned)r]);
#pragma unroll
    for (int p = 0; p < 2; ++p) {
        const int c = lane + p * 64;
        const int row = c >> 3, cq = (c & 7) * 8;
        const long grow = (long)(b * Ls + l0 + w * 16 + row);
        *(short8*)(ao + grow * 1024 + n * 64 + cq) = *(short8*)&psm[w][row][cq];
    }
}

// ---------------------------------------------------------------------------
// LayerNorm in-place over rows of x (4096 x 1024)
// ---------------------------------------------------------------------------
__global__ __launch_bounds__(256) void ln_kernel(
    float* x, const float* __restrict__ g, const float* __restrict__ bb)
{
    const int row = blockIdx.x;
    const int tid = threadIdx.x;
    float4 v = ((const float4*)(x + (long)row * Dd))[tid];
    float s  = v.x + v.y + v.z + v.w;
    float sq = v.x * v.x + v.y * v.y + v.z * v.z + v.w * v.w;
#pragma unroll
    for (int off = 32; off; off >>= 1) {
        s  += __shfl_down(s, off, 64);
        sq += __shfl_down(sq, off, 64);
    }
    __shared__ float ws_s[4], ws_q[4];
    __shared__ float s_mu, s_rstd;
    const int wave = tid >> 6, lane = tid & 63;
    if (lane == 0) { ws_s[wave] = s; ws_q[wave] = sq; }
    __syncthreads();
    if (tid == 0) {
        const float ts = ws_s[0] + ws_s[1] + ws_s[2] + ws_s[3];
        const float tq = ws_q[0] + ws_q[1] + ws_q[2] + ws_q[3];
        const float mu = ts / (float)Dd;
        const float var = tq / (float)Dd - mu * mu;
        s_mu = mu;
        s_rstd = rsqrtf(var + 1e-5f);
    }
    __syncthreads();
    const float mu = s_mu, rstd = s_rstd;
    const float4 gv = ((const float4*)g)[tid];
    const float4 bv = ((const float4*)bb)[tid];
    float4 o;
    o.x = (v.x - mu) * rstd * gv.x + bv.x;
    o.y = (v.y - mu) * rstd * gv.y + bv.y;
    o.z = (v.z - mu) * rstd * gv.z + bv.z;
    o.w = (v.w - mu) * rstd * gv.w + bv.w;
    ((float4*)(x + (long)row * Dd))[tid] = o;
}

// ---------------------------------------------------------------------------
extern "C" void kernel_launch(void* const* d_in, const int* in_sizes, int n_in,
                              void* d_out, int out_size, void* d_ws, size_t ws_size,
                              hipStream_t stream) {
    const float* q      = (const float*)d_in[0];
    const float* k      = (const float*)d_in[1];
    const float* v      = (const float*)d_in[2];
    const float* posenc = (const float*)d_in[3];
    const int*   pad    = (const int*)  d_in[4];
    const float* q_w    = (const float*)d_in[5];
    const float* k_w    = (const float*)d_in[6];
    const float* k_b    = (const float*)d_in[7];
    const float* v_w    = (const float*)d_in[8];
    const float* v_b    = (const float*)d_in[9];
    const float* rwb    = (const float*)d_in[10];
    const float* rrb    = (const float*)d_in[11];
    const float* r_ker  = (const float*)d_in[12];
    const float* post_w = (const float*)d_in[13];
    const float* post_b = (const float*)d_in[14];
    const float* ln_g   = (const float*)d_in[15];
    const float* ln_b   = (const float*)d_in[16];
    float* out = (float*)d_out;

    const long M1 = 1L << 20;                 // 1M elements
    short* ws = (short*)d_ws;
    short* xq   = ws;                         // 4M (z=0 A; aliased by ao later)
    short* xk   = ws + 4 * M1;                // 4M (z=1 A)
    short* xv   = ws + 8 * M1;                // 4M (z=2 A)
    short* pe   = ws + 12 * M1;               // 2M (z=3 A)  == xq + 3*4M
    short* wT   = ws + 14 * M1;               // 3M (qwT,kwT,vwT = z=0..2 B)
    short* rkT  = ws + 17 * M1;               // 1M (z=3 B)  == wT + 3*1M
    short* pwT  = ws + 18 * M1;               // 1M
    short* qh   = ws + 19 * M1;               // 4M (z=0 C)
    short* kh   = ws + 23 * M1;               // 4M (z=1 C)
    short* vh   = ws + 27 * M1;               // 4M (z=2 C)
    short* rS   = ws + 31 * M1;               // 2M (z=3 C)  == qh + 3*4M
    float* bqkv = (float*)(ws + 33 * M1);     // 4096 f32
    short* ao   = xq;                         // alias: xq dead after QKV GEMM

    const dim3 blk(256);

    // ---- prep: convert copies ----
    CopyDesc cd;
    cd.src[0] = q;      cd.dst[0] = xq;  cd.n[0] = 4 * (int)M1;
    cd.src[1] = k;      cd.dst[1] = xk;  cd.n[1] = 4 * (int)M1;
    cd.src[2] = v;      cd.dst[2] = xv;  cd.n[2] = 4 * (int)M1;
    cd.src[3] = posenc; cd.dst[3] = pe;  cd.n[3] = 2 * (int)M1;
    f2bf_multi<<<dim3(2048, 4), blk, 0, stream>>>(cd);

    // ---- prep: weight transposes -> B^T form (batched) ----
    TransDesc td;
    td.src[0] = q_w;    td.dst[0] = wT;
    td.src[1] = k_w;    td.dst[1] = wT + M1;
    td.src[2] = v_w;    td.dst[2] = wT + 2 * M1;
    td.src[3] = post_w; td.dst[3] = pwT;
    transpose4_f2bf<<<dim3(16, 16, 4), blk, 0, stream>>>(td);
    transpose_f2bf<<<dim3(1, 16, 16), blk, 0, stream>>>(r_ker, rkT, 64, 1024,
                                                        (long)1024 * 64, (long)64 * 1024);
    bias_init<<<dim3(16), blk, 0, stream>>>(bqkv, k_b, v_b);

    // ---- merged QKV + r projections (z=0..2: 4096 rows; z=3: 2048 rows) ----
    gemm_bt<<<dim3(8, 32, 4), blk, 0, stream>>>(
        xq, 1024, 4 * M1, wT, 1024, M1, bqkv, 1024,
        nullptr, 0, qh, 1024, 4 * M1, 1, 1024, 16);

    // ---- attention -> ao bf16 ----
    attn_mfma<<<dim3(Ls / 64, Nn, Bb), blk, 0, stream>>>(
        qh, kh, vh, rS, pad, rwb, rrb, ao);

    // ---- post projection + bias + residual -> f32 out ----
    gemm_bt<<<dim3(8, 32, 1), blk, 0, stream>>>(
        ao, 1024, 0, pwT, 1024, 0, post_b, 0,
        q, 1024, out, 1024, 0, 0, 1024, 9999);

    // ---- LayerNorm in-place ----
    ln_kernel<<<dim3(Bb * Ls), blk, 0, stream>>>(out, ln_g, ln_b);
}